// Round 1
// baseline (1944.475 us; speedup 1.0000x reference)
//
#include <hip/hip_runtime.h>
#include <cmath>

#define DM 512        // D_MODEL
#define DS 256        // D_STATE
#define NLAYERS 4
#define BATCH 8
#define SEQ 2048
#define MROWS (BATCH*SEQ)   // 16384

constexpr int BM = 128, BN = 64, BK = 16;
constexpr int TPB = 256;
constexpr int NCHUNK = 32, LCHUNK = 64;   // 32*64 = 2048 = SEQ

__device__ __forceinline__ float sigmoidf_(float v) { return 1.0f / (1.0f + expf(-v)); }

// ---------------------------------------------------------------------------
// Single-W GEMM: O[M,N] = A[M,K] @ W[N,K]^T
// MODE 0: plain store (encoder, decoder)
// MODE 1: z epilogue: O = acc + Dv[col] * xin[row*512 + col]   (N == 512)
// ---------------------------------------------------------------------------
template <int MODE>
__launch_bounds__(TPB)
__global__ void gemm1(const float* __restrict__ A, const float* __restrict__ W,
                      float* __restrict__ O, int M, int N, int K,
                      const float* __restrict__ Dv, const float* __restrict__ xin) {
    __shared__ float As[BK][BM + 4];
    __shared__ float Ws[BK][BN + 4];
    const int m0 = blockIdx.x * BM, n0 = blockIdx.y * BN;
    const int tid = threadIdx.x;
    const int lrow = tid >> 2, lkq = tid & 3;    // loader mapping
    const int tm = tid >> 4, tn = tid & 15;      // compute mapping (16x16)
    float acc[8][4] = {};
    for (int k0 = 0; k0 < K; k0 += BK) {
        float4 a0 = *(const float4*)(A + (size_t)(m0 + lrow) * K + k0 + lkq * 4);
        float4 a1 = *(const float4*)(A + (size_t)(m0 + lrow + 64) * K + k0 + lkq * 4);
        float4 w0 = *(const float4*)(W + (size_t)(n0 + lrow) * K + k0 + lkq * 4);
        __syncthreads();
        As[lkq * 4 + 0][lrow] = a0.x; As[lkq * 4 + 1][lrow] = a0.y;
        As[lkq * 4 + 2][lrow] = a0.z; As[lkq * 4 + 3][lrow] = a0.w;
        As[lkq * 4 + 0][lrow + 64] = a1.x; As[lkq * 4 + 1][lrow + 64] = a1.y;
        As[lkq * 4 + 2][lrow + 64] = a1.z; As[lkq * 4 + 3][lrow + 64] = a1.w;
        Ws[lkq * 4 + 0][lrow] = w0.x; Ws[lkq * 4 + 1][lrow] = w0.y;
        Ws[lkq * 4 + 2][lrow] = w0.z; Ws[lkq * 4 + 3][lrow] = w0.w;
        __syncthreads();
#pragma unroll
        for (int k = 0; k < BK; ++k) {
            float4 av0 = *(const float4*)&As[k][tm * 8];
            float4 av1 = *(const float4*)&As[k][tm * 8 + 4];
            float4 bv  = *(const float4*)&Ws[k][tn * 4];
            float am[8] = {av0.x, av0.y, av0.z, av0.w, av1.x, av1.y, av1.z, av1.w};
            float bn[4] = {bv.x, bv.y, bv.z, bv.w};
#pragma unroll
            for (int i = 0; i < 8; ++i)
#pragma unroll
                for (int j = 0; j < 4; ++j) acc[i][j] = fmaf(am[i], bn[j], acc[i][j]);
        }
    }
    const int c0 = n0 + tn * 4;
#pragma unroll
    for (int i = 0; i < 8; ++i) {
        const int row = m0 + tm * 8 + i;
        float4 v = make_float4(acc[i][0], acc[i][1], acc[i][2], acc[i][3]);
        if (MODE == 1) {
            float4 xv = *(const float4*)(xin + (size_t)row * DM + c0);
            float4 dv = *(const float4*)(Dv + c0);
            v.x += dv.x * xv.x; v.y += dv.y * xv.y; v.z += dv.z * xv.z; v.w += dv.w * xv.w;
        }
        *(float4*)(O + (size_t)row * N + c0) = v;
    }
}

// ---------------------------------------------------------------------------
// Dual-W GEMM: acc0 = A@W0^T, acc1 = A@W1^T
// MODE 0 (Bu): out0[row*512+col] = acc0*gam[col]; out1 (=base+256) same w/ acc1
// MODE 1 (GLU): xbuf[row*512+col] += sig(res[layer]) * acc0 * sigmoid(acc1)
// ---------------------------------------------------------------------------
template <int MODE>
__launch_bounds__(TPB)
__global__ void gemm2(const float* __restrict__ A, const float* __restrict__ W0,
                      const float* __restrict__ W1,
                      float* __restrict__ out0, float* __restrict__ out1,
                      int M, int N, int K,
                      const float* __restrict__ nu,
                      float* __restrict__ xbuf, const float* __restrict__ res, int layer) {
    __shared__ float As[BK][BM + 4];
    __shared__ float Ws0[BK][BN + 4];
    __shared__ float Ws1[BK][BN + 4];
    const int m0 = blockIdx.x * BM, n0 = blockIdx.y * BN;
    const int tid = threadIdx.x;
    const int lrow = tid >> 2, lkq = tid & 3;
    const int tm = tid >> 4, tn = tid & 15;
    float acc0[8][4] = {}, acc1[8][4] = {};
    for (int k0 = 0; k0 < K; k0 += BK) {
        float4 a0 = *(const float4*)(A + (size_t)(m0 + lrow) * K + k0 + lkq * 4);
        float4 a1 = *(const float4*)(A + (size_t)(m0 + lrow + 64) * K + k0 + lkq * 4);
        float4 w0 = *(const float4*)(W0 + (size_t)(n0 + lrow) * K + k0 + lkq * 4);
        float4 w1 = *(const float4*)(W1 + (size_t)(n0 + lrow) * K + k0 + lkq * 4);
        __syncthreads();
        As[lkq * 4 + 0][lrow] = a0.x; As[lkq * 4 + 1][lrow] = a0.y;
        As[lkq * 4 + 2][lrow] = a0.z; As[lkq * 4 + 3][lrow] = a0.w;
        As[lkq * 4 + 0][lrow + 64] = a1.x; As[lkq * 4 + 1][lrow + 64] = a1.y;
        As[lkq * 4 + 2][lrow + 64] = a1.z; As[lkq * 4 + 3][lrow + 64] = a1.w;
        Ws0[lkq * 4 + 0][lrow] = w0.x; Ws0[lkq * 4 + 1][lrow] = w0.y;
        Ws0[lkq * 4 + 2][lrow] = w0.z; Ws0[lkq * 4 + 3][lrow] = w0.w;
        Ws1[lkq * 4 + 0][lrow] = w1.x; Ws1[lkq * 4 + 1][lrow] = w1.y;
        Ws1[lkq * 4 + 2][lrow] = w1.z; Ws1[lkq * 4 + 3][lrow] = w1.w;
        __syncthreads();
#pragma unroll
        for (int k = 0; k < BK; ++k) {
            float4 av0 = *(const float4*)&As[k][tm * 8];
            float4 av1 = *(const float4*)&As[k][tm * 8 + 4];
            float4 b0  = *(const float4*)&Ws0[k][tn * 4];
            float4 b1  = *(const float4*)&Ws1[k][tn * 4];
            float am[8] = {av0.x, av0.y, av0.z, av0.w, av1.x, av1.y, av1.z, av1.w};
            float p0[4] = {b0.x, b0.y, b0.z, b0.w};
            float p1[4] = {b1.x, b1.y, b1.z, b1.w};
#pragma unroll
            for (int i = 0; i < 8; ++i)
#pragma unroll
                for (int j = 0; j < 4; ++j) {
                    acc0[i][j] = fmaf(am[i], p0[j], acc0[i][j]);
                    acc1[i][j] = fmaf(am[i], p1[j], acc1[i][j]);
                }
        }
    }
    const int c0 = n0 + tn * 4;
    if (MODE == 0) {
        float gam[4];
#pragma unroll
        for (int j = 0; j < 4; ++j) {
            float a = expf(-expf(nu[c0 + j]));
            gam[j] = sqrtf(fmaxf(0.f, 1.f - a * a));
        }
#pragma unroll
        for (int i = 0; i < 8; ++i) {
            const int row = m0 + tm * 8 + i;
            float4 vr = make_float4(acc0[i][0] * gam[0], acc0[i][1] * gam[1],
                                    acc0[i][2] * gam[2], acc0[i][3] * gam[3]);
            float4 vi = make_float4(acc1[i][0] * gam[0], acc1[i][1] * gam[1],
                                    acc1[i][2] * gam[2], acc1[i][3] * gam[3]);
            *(float4*)(out0 + (size_t)row * DM + c0) = vr;
            *(float4*)(out1 + (size_t)row * DM + c0) = vi;
        }
    } else {
        const float rs = sigmoidf_(res[layer]);
#pragma unroll
        for (int i = 0; i < 8; ++i) {
            const int row = m0 + tm * 8 + i;
            float4 xv = *(const float4*)(xbuf + (size_t)row * DM + c0);
            xv.x += rs * acc0[i][0] * sigmoidf_(acc1[i][0]);
            xv.y += rs * acc0[i][1] * sigmoidf_(acc1[i][1]);
            xv.z += rs * acc0[i][2] * sigmoidf_(acc1[i][2]);
            xv.w += rs * acc0[i][3] * sigmoidf_(acc1[i][3]);
            *(float4*)(xbuf + (size_t)row * DM + c0) = xv;
        }
    }
}

// ---------------------------------------------------------------------------
// Wz prep: Wz[layer][d][k] = k<256 ? Cre[layer][d][k] : -Cim[layer][d][k-256]
// ---------------------------------------------------------------------------
__global__ void prep_wz(const float* __restrict__ Cre, const float* __restrict__ Cim,
                        float* __restrict__ Wz) {
    int idx = blockIdx.x * 256 + threadIdx.x;     // over 4*512*512
    int k = idx & 511;
    int d = (idx >> 9) & 511;
    int layer = idx >> 18;
    float v = (k < DS) ? Cre[((size_t)layer * DM + d) * DS + k]
                       : -Cim[((size_t)layer * DM + d) * DS + (k - DS)];
    Wz[idx] = v;
}

// ---------------------------------------------------------------------------
// Chunked diagonal complex scan, in place on BuH [MROWS][512] (re | im)
// ---------------------------------------------------------------------------
__global__ void scan_local(float* __restrict__ BuH, const float* __restrict__ nu,
                           const float* __restrict__ th, float* __restrict__ carry) {
    const int n = threadIdx.x;
    const int b = blockIdx.x / NCHUNK, c = blockIdx.x % NCHUNK;
    float a = expf(-expf(nu[n])), t = expf(th[n]);
    float lre = a * cosf(t), lim = a * sinf(t);
    float hre = 0.f, him = 0.f;
    size_t base = ((size_t)b * SEQ + (size_t)c * LCHUNK) * DM + n;
#pragma unroll 4
    for (int i = 0; i < LCHUNK; ++i, base += DM) {
        float bre = BuH[base], bim = BuH[base + DS];
        float nr = fmaf(lre, hre, fmaf(-lim, him, bre));
        float ni = fmaf(lre, him, fmaf(lim, hre, bim));
        hre = nr; him = ni;
        BuH[base] = hre; BuH[base + DS] = him;
    }
    carry[(size_t)blockIdx.x * DM + n] = hre;
    carry[(size_t)blockIdx.x * DM + DS + n] = him;
}

__global__ void scan_carry(float* __restrict__ carry, const float* __restrict__ nu,
                           const float* __restrict__ th) {
    const int n = threadIdx.x;
    const int b = blockIdx.x;
    float a = expf(-expf(nu[n])), t = expf(th[n]);
    float lre = a * cosf(t), lim = a * sinf(t);
    float pre = lre, pim = lim;                 // lam^(2^s), Lc = 64 = 2^6
    for (int s = 0; s < 6; ++s) {
        float nr = pre * pre - pim * pim;
        float ni = 2.f * pre * pim;
        pre = nr; pim = ni;
    }
    size_t base = (size_t)b * NCHUNK * DM + n;
    float gre = carry[base], gim = carry[base + DS];
    for (int c = 1; c < NCHUNK; ++c) {
        size_t idx = base + (size_t)c * DM;
        float cr = carry[idx], ci = carry[idx + DS];
        float nr = fmaf(pre, gre, fmaf(-pim, gim, cr));
        float ni = fmaf(pre, gim, fmaf(pim, gre, ci));
        gre = nr; gim = ni;
        carry[idx] = gre; carry[idx + DS] = gim;
    }
}

__global__ void scan_fix(float* __restrict__ BuH, const float* __restrict__ nu,
                         const float* __restrict__ th, const float* __restrict__ carry) {
    const int n = threadIdx.x;
    const int b = blockIdx.x / (NCHUNK - 1);
    const int c = blockIdx.x % (NCHUNK - 1) + 1;
    float a = expf(-expf(nu[n])), t = expf(th[n]);
    float lre = a * cosf(t), lim = a * sinf(t);
    size_t cb = ((size_t)b * NCHUNK + (c - 1)) * DM + n;
    float gre = carry[cb], gim = carry[cb + DS];
    float pre = lre, pim = lim;                 // lam^(i+1)
    size_t base = ((size_t)b * SEQ + (size_t)c * LCHUNK) * DM + n;
#pragma unroll 4
    for (int i = 0; i < LCHUNK; ++i, base += DM) {
        float hre = BuH[base], him = BuH[base + DS];
        hre = fmaf(pre, gre, fmaf(-pim, gim, hre));
        him = fmaf(pre, gim, fmaf(pim, gre, him));
        BuH[base] = hre; BuH[base + DS] = him;
        float nr = pre * lre - pim * lim;
        float ni = pre * lim + pim * lre;
        pre = nr; pim = ni;
    }
}

// ---------------------------------------------------------------------------
extern "C" void kernel_launch(void* const* d_in, const int* in_sizes, int n_in,
                              void* d_out, int out_size, void* d_ws, size_t ws_size,
                              hipStream_t stream) {
    const float* u   = (const float*)d_in[0];
    const float* enc = (const float*)d_in[1];
    const float* dec = (const float*)d_in[2];
    const float* nu  = (const float*)d_in[3];
    const float* th  = (const float*)d_in[4];
    const float* Bre = (const float*)d_in[5];
    const float* Bim = (const float*)d_in[6];
    const float* Cre = (const float*)d_in[7];
    const float* Cim = (const float*)d_in[8];
    const float* Dp  = (const float*)d_in[9];
    const float* W1  = (const float*)d_in[10];
    const float* W2  = (const float*)d_in[11];
    const float* res = (const float*)d_in[12];
    float* out = (float*)d_out;

    float* ws    = (float*)d_ws;
    float* x     = ws;                                  // [16384,512]
    float* z     = x + (size_t)MROWS * DM;              // [16384,512]
    float* BuH   = z + (size_t)MROWS * DM;              // [16384,512] re|im
    float* Wz    = BuH + (size_t)MROWS * DM;            // [4,512,512]
    float* carry = Wz + (size_t)NLAYERS * DM * DM;      // [8,32,512]

    prep_wz<<<NLAYERS * DM * DM / 256, 256, 0, stream>>>(Cre, Cim, Wz);

    // encoder: x = u @ enc^T   (M=16384, N=512, K=64)
    gemm1<0><<<dim3(MROWS / BM, DM / BN), TPB, 0, stream>>>(u, enc, x, MROWS, DM, 64,
                                                           nullptr, nullptr);
    for (int k = 0; k < NLAYERS; ++k) {
        const float* nuk = nu + k * DS;
        const float* thk = th + k * DS;
        // Bu (dual, gamma scale): BuH[:,0:256]=x@Bre^T*g, BuH[:,256:512]=x@Bim^T*g
        gemm2<0><<<dim3(MROWS / BM, DS / BN), TPB, 0, stream>>>(
            x, Bre + (size_t)k * DS * DM, Bim + (size_t)k * DS * DM,
            BuH, BuH + DS, MROWS, DS, DM, nuk, nullptr, nullptr, 0);
        // scan in place
        scan_local<<<BATCH * NCHUNK, 256, 0, stream>>>(BuH, nuk, thk, carry);
        scan_carry<<<BATCH, 256, 0, stream>>>(carry, nuk, thk);
        scan_fix<<<BATCH * (NCHUNK - 1), 256, 0, stream>>>(BuH, nuk, thk, carry);
        // z = Re(h @ C^T) + D*x  (single GEMM over packed K=512 with prepped Wz)
        gemm1<1><<<dim3(MROWS / BM, DM / BN), TPB, 0, stream>>>(
            BuH, Wz + (size_t)k * DM * DM, z, MROWS, DM, DM, Dp + k * DM, x);
        // GLU + gated residual: x += sig(res)*[(z@W1^T)*sigmoid(z@W2^T)]
        gemm2<1><<<dim3(MROWS / BM, DM / BN), TPB, 0, stream>>>(
            z, W1 + (size_t)k * DM * DM, W2 + (size_t)k * DM * DM,
            nullptr, nullptr, MROWS, DM, DM, nullptr, x, res, k);
    }
    // decoder: out = x @ dec^T  (M=16384, N=64, K=512)
    gemm1<0><<<dim3(MROWS / BM, 64 / BN), TPB, 0, stream>>>(x, dec, out, MROWS, 64, DM,
                                                           nullptr, nullptr);
}

// Round 2
// 866.681 us; speedup vs baseline: 2.2436x; 2.2436x over previous
//
#include <hip/hip_runtime.h>
#include <cmath>

#define DM 512
#define DS 256
#define NL 4
#define BATCH 8
#define SEQ 2048
#define MROWS (BATCH*SEQ)   // 16384
#define NCHUNK 32
#define LCHUNK 64

typedef unsigned short ushort_t;
typedef __attribute__((ext_vector_type(8))) short short8;
typedef __attribute__((ext_vector_type(4))) float floatx4;

__device__ __forceinline__ float sigmoidf_(float v) { return 1.0f / (1.0f + __expf(-v)); }

__device__ __forceinline__ ushort_t f2bf(float f) {
    union { float f; unsigned int u; } c; c.f = f;
    unsigned int u = c.u;
    u += 0x7fffu + ((u >> 16) & 1u);          // RNE
    return (ushort_t)(u >> 16);
}

// ---------------------------------------------------------------------------
// bf16 MFMA GEMM: O[M,N] = A[M,K](bf16) @ W[N,K](bf16)^T, fp32 accumulate.
// 128xBN tile, 4 waves, 16x16x32 MFMA. EPI:
//  0: encoder  -> of32 = acc ; obf = bf16(acc)
//  1: Bu       -> of32 = acc * gam[col&255]
//  2: z        -> obf  = bf16(acc + Dv[col]*xf32[row,col])
//  3: GLU dual -> xf32 += sigmoid(resp[layer])*acc0*sigmoid(acc1); obf=bf16(xf32)
//  4: plain    -> of32 = acc   (decoder)
// ---------------------------------------------------------------------------
template<int BN, int EPI, int DUAL>
__launch_bounds__(256, DUAL ? 2 : 3)
__global__ void mgemm(const ushort_t* __restrict__ A,
                      const ushort_t* __restrict__ Wa,
                      const ushort_t* __restrict__ Wb,
                      int K, int N,
                      float* __restrict__ of32,
                      ushort_t* __restrict__ obf,
                      const float* __restrict__ gam,
                      const float* __restrict__ Dv,
                      float* __restrict__ xf32,
                      const float* __restrict__ resp, int layer) {
    constexpr int BM = 128;
    constexpr int MT = (BN == 128) ? 4 : 2;   // 16-row m-tiles per wave
    constexpr int NT = 4;                     // 16-col n-tiles per wave
    constexpr int LDP = 40;                   // LDS row pitch (bf16 elems), +8 pad
    __shared__ ushort_t As[BM * LDP];
    __shared__ ushort_t Bs0[BN * LDP];
    __shared__ ushort_t Bs1[DUAL ? BN * LDP : 64];

    const int tid = threadIdx.x, lane = tid & 63, wid = tid >> 6;
    const int wm = (BN == 128) ? (wid & 1) : wid;
    const int wn = (BN == 128) ? (wid >> 1) : 0;
    const int m0 = blockIdx.x * BM, n0 = blockIdx.y * BN;
    const int q = lane >> 4, r16 = lane & 15;
    constexpr int BCH = (BN * 4) / 256;       // B 16B-chunks per thread

    floatx4 acc0[MT][NT] = {};
    floatx4 acc1[DUAL ? MT : 1][DUAL ? NT : 1] = {};

    for (int k0 = 0; k0 < K; k0 += 32) {
        uint4 ra[2], rb0[BCH], rb1[DUAL ? BCH : 1];
#pragma unroll
        for (int i = 0; i < 2; ++i) {
            int c = tid + i * 256, rr = c >> 2, qq = c & 3;
            ra[i] = *(const uint4*)(A + (size_t)(m0 + rr) * K + k0 + qq * 8);
        }
#pragma unroll
        for (int i = 0; i < BCH; ++i) {
            int c = tid + i * 256, rr = c >> 2, qq = c & 3;
            rb0[i] = *(const uint4*)(Wa + (size_t)(n0 + rr) * K + k0 + qq * 8);
            if constexpr (DUAL) rb1[i] = *(const uint4*)(Wb + (size_t)(n0 + rr) * K + k0 + qq * 8);
        }
        __syncthreads();
#pragma unroll
        for (int i = 0; i < 2; ++i) {
            int c = tid + i * 256, rr = c >> 2, qq = c & 3;
            *(uint4*)&As[rr * LDP + qq * 8] = ra[i];
        }
#pragma unroll
        for (int i = 0; i < BCH; ++i) {
            int c = tid + i * 256, rr = c >> 2, qq = c & 3;
            *(uint4*)&Bs0[rr * LDP + qq * 8] = rb0[i];
            if constexpr (DUAL) *(uint4*)&Bs1[rr * LDP + qq * 8] = rb1[i];
        }
        __syncthreads();

        short8 af[MT], b0[NT], b1[DUAL ? NT : 1];
#pragma unroll
        for (int i = 0; i < MT; ++i)
            af[i] = *(const short8*)&As[(wm * MT * 16 + i * 16 + r16) * LDP + q * 8];
#pragma unroll
        for (int j = 0; j < NT; ++j) {
            b0[j] = *(const short8*)&Bs0[(wn * 64 + j * 16 + r16) * LDP + q * 8];
            if constexpr (DUAL) b1[j] = *(const short8*)&Bs1[(wn * 64 + j * 16 + r16) * LDP + q * 8];
        }
#pragma unroll
        for (int i = 0; i < MT; ++i)
#pragma unroll
            for (int j = 0; j < NT; ++j) {
                acc0[i][j] = __builtin_amdgcn_mfma_f32_16x16x32_bf16(af[i], b0[j], acc0[i][j], 0, 0, 0);
                if constexpr (DUAL)
                    acc1[i][j] = __builtin_amdgcn_mfma_f32_16x16x32_bf16(af[i], b1[j], acc1[i][j], 0, 0, 0);
            }
    }

    float rsv = 0.f;
    if constexpr (EPI == 3) rsv = sigmoidf_(resp[layer]);
#pragma unroll
    for (int i = 0; i < MT; ++i)
#pragma unroll
        for (int j = 0; j < NT; ++j)
#pragma unroll
            for (int rr = 0; rr < 4; ++rr) {
                const int row = m0 + wm * MT * 16 + i * 16 + q * 4 + rr;
                const int col = n0 + wn * 64 + j * 16 + r16;
                const float v = acc0[i][j][rr];
                if constexpr (EPI == 0) {
                    of32[(size_t)row * N + col] = v;
                    obf[(size_t)row * N + col] = f2bf(v);
                } else if constexpr (EPI == 1) {
                    of32[(size_t)row * N + col] = v * gam[col & 255];
                } else if constexpr (EPI == 2) {
                    float zv = v + Dv[col] * xf32[(size_t)row * N + col];
                    obf[(size_t)row * N + col] = f2bf(zv);
                } else if constexpr (EPI == 3) {
                    float g = rsv * v * sigmoidf_(acc1[i][j][rr]);
                    float xn = xf32[(size_t)row * N + col] + g;
                    xf32[(size_t)row * N + col] = xn;
                    obf[(size_t)row * N + col] = f2bf(xn);
                } else {
                    of32[(size_t)row * N + col] = v;
                }
            }
}

// ---------------------------------------------------------------------------
// Weight prep: bf16 casts + packing. idx over 4*512*512.
// WB[l][n][k]  = n<256 ? Bre[l][n][k] : Bim[l][n-256][k]
// Wz[l][d][k]  = k<256 ? Cre[l][d][k] : -Cim[l][d][k-256]
// ---------------------------------------------------------------------------
__global__ void prep_w(const float* __restrict__ Bre, const float* __restrict__ Bim,
                       const float* __restrict__ Cre, const float* __restrict__ Cim,
                       const float* __restrict__ W1, const float* __restrict__ W2,
                       const float* __restrict__ enc, const float* __restrict__ dec,
                       ushort_t* __restrict__ WBb, ushort_t* __restrict__ Wzb,
                       ushort_t* __restrict__ W1b, ushort_t* __restrict__ W2b,
                       ushort_t* __restrict__ encb, ushort_t* __restrict__ decb) {
    const int idx = blockIdx.x * 256 + threadIdx.x;       // 0..4*512*512-1
    const int k = idx & 511, n = (idx >> 9) & 511, l = idx >> 18;
    WBb[idx] = f2bf(n < 256 ? Bre[((size_t)(l * 256 + n)) * 512 + k]
                            : Bim[((size_t)(l * 256 + (n - 256))) * 512 + k]);
    Wzb[idx] = f2bf(k < 256 ? Cre[((size_t)(l * 512 + n)) * 256 + k]
                            : -Cim[((size_t)(l * 512 + n)) * 256 + (k - 256)]);
    W1b[idx] = f2bf(W1[idx]);
    W2b[idx] = f2bf(W2[idx]);
    if (idx < 512 * 64) { encb[idx] = f2bf(enc[idx]); decb[idx] = f2bf(dec[idx]); }
}

__global__ void prep_u(const float* __restrict__ u, ushort_t* __restrict__ ubf) {
    const int idx = blockIdx.x * 256 + threadIdx.x;       // 16384*64
    ubf[idx] = f2bf(u[idx]);
}

__global__ void prep_tab(const float* __restrict__ nu, const float* __restrict__ th,
                         float* __restrict__ lre, float* __restrict__ lim,
                         float* __restrict__ gm) {
    const int idx = blockIdx.x * 256 + threadIdx.x;       // 4*256
    float a = expf(-expf(nu[idx])), t = expf(th[idx]);
    lre[idx] = a * cosf(t);
    lim[idx] = a * sinf(t);
    gm[idx] = sqrtf(fmaxf(0.f, 1.f - a * a));
}

// ---------------------------------------------------------------------------
// Scan: pass1 chunk end-states only; carry prefix; pass2 recompute + emit bf16 h
// ---------------------------------------------------------------------------
__global__ void scan_ends(const float* __restrict__ BuH, const float* __restrict__ lret,
                          const float* __restrict__ limt, float* __restrict__ carry) {
    const int n = threadIdx.x;
    const int b = blockIdx.x >> 5, c = blockIdx.x & 31;
    const float lre = lret[n], lim = limt[n];
    float hre = 0.f, him = 0.f;
    size_t base = ((size_t)b * SEQ + (size_t)c * LCHUNK) * DM + n;
#pragma unroll 4
    for (int i = 0; i < LCHUNK; ++i, base += DM) {
        float br = BuH[base], bi = BuH[base + DS];
        float nr = fmaf(lre, hre, fmaf(-lim, him, br));
        float ni = fmaf(lre, him, fmaf(lim, hre, bi));
        hre = nr; him = ni;
    }
    carry[(size_t)blockIdx.x * DM + n] = hre;
    carry[(size_t)blockIdx.x * DM + DS + n] = him;
}

__global__ void scan_carry(float* __restrict__ carry, const float* __restrict__ lret,
                           const float* __restrict__ limt) {
    const int n = threadIdx.x;
    const int b = blockIdx.x;
    float pre = lret[n], pim = limt[n];
    for (int s = 0; s < 6; ++s) {            // lam^64
        float nr = pre * pre - pim * pim, ni = 2.f * pre * pim;
        pre = nr; pim = ni;
    }
    size_t base = (size_t)b * NCHUNK * DM + n;
    float gre = carry[base], gim = carry[base + DS];
    for (int c = 1; c < NCHUNK; ++c) {
        size_t id = base + (size_t)c * DM;
        float cr = carry[id], ci = carry[id + DS];
        float nr = fmaf(pre, gre, fmaf(-pim, gim, cr));
        float ni = fmaf(pre, gim, fmaf(pim, gre, ci));
        gre = nr; gim = ni;
        carry[id] = gre; carry[id + DS] = gim;
    }
}

__global__ void scan_apply(const float* __restrict__ BuH, const float* __restrict__ lret,
                           const float* __restrict__ limt, const float* __restrict__ carry,
                           ushort_t* __restrict__ hbf) {
    const int n = threadIdx.x;
    const int b = blockIdx.x >> 5, c = blockIdx.x & 31;
    const float lre = lret[n], lim = limt[n];
    float hre = 0.f, him = 0.f;
    if (c > 0) {
        size_t cb = (size_t)(blockIdx.x - 1) * DM + n;
        hre = carry[cb]; him = carry[cb + DS];
    }
    size_t base = ((size_t)b * SEQ + (size_t)c * LCHUNK) * DM + n;
#pragma unroll 4
    for (int i = 0; i < LCHUNK; ++i, base += DM) {
        float br = BuH[base], bi = BuH[base + DS];
        float nr = fmaf(lre, hre, fmaf(-lim, him, br));
        float ni = fmaf(lre, him, fmaf(lim, hre, bi));
        hre = nr; him = ni;
        hbf[base] = f2bf(hre); hbf[base + DS] = f2bf(him);
    }
}

// ---------------------------------------------------------------------------
extern "C" void kernel_launch(void* const* d_in, const int* in_sizes, int n_in,
                              void* d_out, int out_size, void* d_ws, size_t ws_size,
                              hipStream_t stream) {
    const float* u   = (const float*)d_in[0];
    const float* enc = (const float*)d_in[1];
    const float* dec = (const float*)d_in[2];
    const float* nu  = (const float*)d_in[3];
    const float* th  = (const float*)d_in[4];
    const float* Bre = (const float*)d_in[5];
    const float* Bim = (const float*)d_in[6];
    const float* Cre = (const float*)d_in[7];
    const float* Cim = (const float*)d_in[8];
    const float* Dp  = (const float*)d_in[9];
    const float* W1  = (const float*)d_in[10];
    const float* W2  = (const float*)d_in[11];
    const float* res = (const float*)d_in[12];
    float* out = (float*)d_out;

    const size_t MD = (size_t)MROWS * DM;      // 8,388,608
    float* x     = (float*)d_ws;               // [16384,512] fp32
    float* BuH   = x + MD;                     // [16384,512] fp32 (z_bf aliases)
    float* carry = BuH + MD;                   // [256,512]
    float* lre   = carry + (size_t)BATCH * NCHUNK * DM;
    float* lim   = lre + NL * DS;
    float* gmt   = lim + NL * DS;
    ushort_t* xbf = (ushort_t*)(gmt + NL * DS);     // [16384,512] bf16
    ushort_t* hbf = xbf + MD;                       // [16384,512] bf16 (u_bf aliases)
    ushort_t* zbf = (ushort_t*)BuH;                 // alias: BuH dead before z written
    ushort_t* ubf = hbf;                            // alias: h first written after u consumed
    ushort_t* WBb = hbf + MD;                       // 4x512x512 bf16 each:
    ushort_t* Wzb = WBb + (size_t)NL * DM * DM;
    ushort_t* W1b = Wzb + (size_t)NL * DM * DM;
    ushort_t* W2b = W1b + (size_t)NL * DM * DM;
    ushort_t* encb = W2b + (size_t)NL * DM * DM;    // 512x64
    ushort_t* decb = encb + DM * 64;                // 64x512

    prep_w<<<NL * DM * DM / 256, 256, 0, stream>>>(Bre, Bim, Cre, Cim, W1, W2, enc, dec,
                                                   WBb, Wzb, W1b, W2b, encb, decb);
    prep_u<<<MROWS * 64 / 256, 256, 0, stream>>>(u, ubf);
    prep_tab<<<NL, 256, 0, stream>>>(nu, th, lre, lim, gmt);

    // encoder: x = u @ enc^T  (fp32 + bf16 mirrors)
    mgemm<128, 0, 0><<<dim3(MROWS / 128, DM / 128), 256, 0, stream>>>(
        ubf, encb, nullptr, 64, DM, x, xbf, nullptr, nullptr, nullptr, nullptr, 0);

    for (int k = 0; k < NL; ++k) {
        // Bu = (x @ WB^T) * gamma  -> BuH fp32
        mgemm<128, 1, 0><<<dim3(MROWS / 128, DM / 128), 256, 0, stream>>>(
            xbf, WBb + (size_t)k * DM * DM, nullptr, DM, DM, BuH, nullptr,
            gmt + k * DS, nullptr, nullptr, nullptr, 0);
        scan_ends<<<BATCH * NCHUNK, 256, 0, stream>>>(BuH, lre + k * DS, lim + k * DS, carry);
        scan_carry<<<BATCH, 256, 0, stream>>>(carry, lre + k * DS, lim + k * DS);
        scan_apply<<<BATCH * NCHUNK, 256, 0, stream>>>(BuH, lre + k * DS, lim + k * DS,
                                                       carry, hbf);
        // z = Re(h @ C^T) + D*x  -> z_bf
        mgemm<128, 2, 0><<<dim3(MROWS / 128, DM / 128), 256, 0, stream>>>(
            hbf, Wzb + (size_t)k * DM * DM, nullptr, DM, DM, nullptr, zbf,
            nullptr, Dp + k * DM, x, nullptr, 0);
        // x += sig(res)*[(z@W1^T)*sigmoid(z@W2^T)]  -> x fp32 + x_bf
        mgemm<128, 3, 1><<<dim3(MROWS / 128, DM / 128), 256, 0, stream>>>(
            zbf, W1b + (size_t)k * DM * DM, W2b + (size_t)k * DM * DM, DM, DM,
            nullptr, xbf, nullptr, nullptr, x, res, k);
    }
    // decoder: out = x @ dec^T
    mgemm<64, 4, 0><<<dim3(MROWS / 128, 1), 256, 0, stream>>>(
        xbf, decb, nullptr, DM, 64, out, nullptr, nullptr, nullptr, nullptr, nullptr, 0);
}

// Round 3
// 463.028 us; speedup vs baseline: 4.1995x; 1.8718x over previous
//
#include <hip/hip_runtime.h>
#include <cmath>

#define DM 512
#define DS 256
#define NL 4
#define BATCH 8
#define SEQ 2048
#define MROWS (BATCH*SEQ)   // 16384
#define NCHUNK 32
#define LCHUNK 64

typedef unsigned short ushort_t;
typedef unsigned int uint_t;
typedef __attribute__((ext_vector_type(8))) short short8;
typedef __attribute__((ext_vector_type(4))) float floatx4;

__device__ __forceinline__ float sigmoidf_(float v) { return 1.0f / (1.0f + __expf(-v)); }

__device__ __forceinline__ ushort_t f2bf(float f) {
    union { float f; unsigned int u; } c; c.f = f;
    unsigned int u = c.u;
    u += 0x7fffu + ((u >> 16) & 1u);          // RNE
    return (ushort_t)(u >> 16);
}
__device__ __forceinline__ float bf2f(uint_t h) {
    union { unsigned int u; float f; } c; c.u = (h & 0xffffu) << 16; return c.f;
}
__device__ __forceinline__ uint_t pack2(float a, float b) {
    return (uint_t)f2bf(a) | ((uint_t)f2bf(b) << 16);
}

#define AS1 __attribute__((address_space(1)))
#define AS3 __attribute__((address_space(3)))
__device__ __forceinline__ void gl_lds16(const void* g, void* l) {
    __builtin_amdgcn_global_load_lds((const AS1 uint_t*)g, (AS3 uint_t*)l, 16, 0, 0);
}

// ---------------------------------------------------------------------------
// bf16 MFMA GEMM, async global->LDS staging (m97 pattern), LDS-transpose
// epilogue for fully coalesced output/x traffic.
// O = A[M,K] @ W[N,K]^T. EPI:
//  0: encoder  -> of32 = acc ; obf = bf16(acc)
//  1: Bu       -> obf  = bf16(acc * gam[(col)>>1])     (interleaved re/im cols)
//  2: z        -> obf  = bf16(acc + Dv[col]*xf32[row,col])
//  3: GLU dual -> xf32 += sigmoid(resp[l])*acc0*sigmoid(acc1); obf = bf16(xf32)
//  4: plain    -> of32 = acc   (decoder, BN=64, direct store)
// ---------------------------------------------------------------------------
template<int BN, int EPI, int DUAL>
__launch_bounds__(256, DUAL ? 2 : 3)
__global__ void mgemm(const ushort_t* __restrict__ A,
                      const ushort_t* __restrict__ Wa,
                      const ushort_t* __restrict__ Wb,
                      int K, int N,
                      float* __restrict__ of32,
                      ushort_t* __restrict__ obf,
                      const float* __restrict__ gam,
                      const float* __restrict__ Dv,
                      float* __restrict__ xf32,
                      const float* __restrict__ resp, int layer) {
    constexpr int BM = 128;
    constexpr int MT = (BN == 128) ? 4 : 2;   // 16-row tiles per wave (M)
    constexpr int NT = 4;                     // 16-col tiles per wave (N)
    constexpr int WROWS = MT * 16;
    constexpr int STG = 8192 + (BN == 128 ? 8192 : 4096) + (DUAL ? 8192 : 0);
    constexpr int EPB = (BN == 128) ? 32 * 132 * 4 : 0;
    constexpr int SMB = (STG > EPB) ? STG : EPB;
    __shared__ char smem[SMB];
    ushort_t* As  = (ushort_t*)smem;                 // [128][32] bf16, 64B rows
    ushort_t* Bs0 = (ushort_t*)(smem + 8192);
    ushort_t* Bs1 = (ushort_t*)(smem + 16384);
    float*    eps = (float*)smem;                    // epilogue scratch [32][132]

    const int tid = threadIdx.x, lane = tid & 63, wid = tid >> 6;
    const int wm = (BN == 128) ? (wid & 1) : wid;
    const int wn = (BN == 128) ? (wid >> 1) : 0;
    const int m0 = blockIdx.x * BM, n0 = blockIdx.y * BN;
    const int q = lane >> 4, r16 = lane & 15;
    const int lrow = lane >> 2;                      // async-load row within chunk
    const size_t Kb = (size_t)K * 2;                 // row bytes
    const char* Ap  = (const char*)A  + (size_t)m0 * Kb + (lane & 3) * 16;
    const char* B0p = (const char*)Wa + (size_t)n0 * Kb + (lane & 3) * 16;
    const char* B1p = DUAL ? (const char*)Wb + (size_t)n0 * Kb + (lane & 3) * 16 : nullptr;

    floatx4 acc0[MT][NT] = {};
    floatx4 acc1[DUAL ? MT : 1][DUAL ? NT : 1] = {};

    for (int k0 = 0; k0 < K; k0 += 32) {
        __syncthreads();
        const size_t kb = (size_t)k0 * 2;
        // A: 8 chunks of 16 rows, 2 per wave
        gl_lds16(Ap + (size_t)(wid * 16 + lrow) * Kb + kb, smem + wid * 1024);
        gl_lds16(Ap + (size_t)((wid + 4) * 16 + lrow) * Kb + kb, smem + (wid + 4) * 1024);
        // B
        gl_lds16(B0p + (size_t)(wid * 16 + lrow) * Kb + kb, smem + 8192 + wid * 1024);
        if constexpr (BN == 128)
            gl_lds16(B0p + (size_t)((wid + 4) * 16 + lrow) * Kb + kb,
                     smem + 8192 + (wid + 4) * 1024);
        if constexpr (DUAL) {
            gl_lds16(B1p + (size_t)(wid * 16 + lrow) * Kb + kb, smem + 16384 + wid * 1024);
            gl_lds16(B1p + (size_t)((wid + 4) * 16 + lrow) * Kb + kb,
                     smem + 16384 + (wid + 4) * 1024);
        }
        __syncthreads();

        short8 af[MT], b0[NT], b1[DUAL ? NT : 1];
#pragma unroll
        for (int i = 0; i < MT; ++i)
            af[i] = *(const short8*)&As[(wm * WROWS + i * 16 + r16) * 32 + q * 8];
#pragma unroll
        for (int j = 0; j < NT; ++j) {
            b0[j] = *(const short8*)&Bs0[(wn * 64 + j * 16 + r16) * 32 + q * 8];
            if constexpr (DUAL)
                b1[j] = *(const short8*)&Bs1[(wn * 64 + j * 16 + r16) * 32 + q * 8];
        }
#pragma unroll
        for (int i = 0; i < MT; ++i)
#pragma unroll
            for (int j = 0; j < NT; ++j) {
                acc0[i][j] = __builtin_amdgcn_mfma_f32_16x16x32_bf16(af[i], b0[j], acc0[i][j], 0, 0, 0);
                if constexpr (DUAL)
                    acc1[i][j] = __builtin_amdgcn_mfma_f32_16x16x32_bf16(af[i], b1[j], acc1[i][j], 0, 0, 0);
            }
    }

    if constexpr (EPI == 4) {
        // decoder: direct fp32 stores
#pragma unroll
        for (int i = 0; i < MT; ++i)
#pragma unroll
            for (int j = 0; j < NT; ++j)
#pragma unroll
                for (int rr = 0; rr < 4; ++rr) {
                    const int row = m0 + wm * WROWS + i * 16 + q * 4 + rr;
                    const int col = wn * 64 + j * 16 + r16;
                    of32[(size_t)row * N + col] = acc0[i][j][rr];
                }
        return;
    }

    float rsv = 0.f;
    if constexpr (EPI == 3) rsv = sigmoidf_(resp[layer]);

#pragma unroll
    for (int i = 0; i < MT; ++i) {
        __syncthreads();
#pragma unroll
        for (int j = 0; j < NT; ++j) {
            const int colt = wn * 64 + j * 16 + r16;
#pragma unroll
            for (int rr = 0; rr < 4; ++rr) {
                float v = acc0[i][j][rr];
                if constexpr (EPI == 1) v *= gam[(n0 + colt) >> 1];
                if constexpr (EPI == 3) v = rsv * v * sigmoidf_(acc1[i][j][rr]);
                eps[(wm * 16 + q * 4 + rr) * 132 + colt] = v;
            }
        }
        __syncthreads();
        // coalesced read-back: thread -> (row_r = tid>>3, 16 cols at (tid&7)*16)
        const int row_r = tid >> 3, colg = (tid & 7) * 16;
        const int grow = m0 + (row_r >> 4) * 64 + i * 16 + (row_r & 15);
        const int gcol = n0 + colg;
        float4 f[4];
#pragma unroll
        for (int c = 0; c < 4; ++c) f[c] = *(float4*)&eps[row_r * 132 + colg + c * 4];
        const size_t ob = (size_t)grow * N + gcol;

        if constexpr (EPI == 0) {
#pragma unroll
            for (int c = 0; c < 4; ++c) *(float4*)(of32 + ob + c * 4) = f[c];
        } else if constexpr (EPI == 2) {
#pragma unroll
            for (int c = 0; c < 4; ++c) {
                float4 xv = *(const float4*)(xf32 + ob + c * 4);
                float4 dv = *(const float4*)(Dv + gcol + c * 4);
                f[c].x += dv.x * xv.x; f[c].y += dv.y * xv.y;
                f[c].z += dv.z * xv.z; f[c].w += dv.w * xv.w;
            }
        } else if constexpr (EPI == 3) {
#pragma unroll
            for (int c = 0; c < 4; ++c) {
                float4 xv = *(const float4*)(xf32 + ob + c * 4);
                f[c].x += xv.x; f[c].y += xv.y; f[c].z += xv.z; f[c].w += xv.w;
                *(float4*)(xf32 + ob + c * 4) = f[c];
            }
        }
        // bf16 store (all EPI 0..3 write obf)
        uint4 p0, p1;
        p0.x = pack2(f[0].x, f[0].y); p0.y = pack2(f[0].z, f[0].w);
        p0.z = pack2(f[1].x, f[1].y); p0.w = pack2(f[1].z, f[1].w);
        p1.x = pack2(f[2].x, f[2].y); p1.y = pack2(f[2].z, f[2].w);
        p1.z = pack2(f[3].x, f[3].y); p1.w = pack2(f[3].z, f[3].w);
        *(uint4*)(obf + ob) = p0;
        *(uint4*)(obf + ob + 8) = p1;
    }
}

// ---------------------------------------------------------------------------
// Weight prep. Interleaved complex layouts:
//  WBb rows: n -> state s=n>>1, part n&1 (0=re,1=im):   WBb[l][n][k]
//  Wzb cols: k -> state s=k>>1, part k&1 (re, -im):     Wzb[l][d][k]
// ---------------------------------------------------------------------------
__global__ void prep_w(const float* __restrict__ Bre, const float* __restrict__ Bim,
                       const float* __restrict__ Cre, const float* __restrict__ Cim,
                       const float* __restrict__ W1, const float* __restrict__ W2,
                       const float* __restrict__ enc, const float* __restrict__ dec,
                       ushort_t* __restrict__ WBb, ushort_t* __restrict__ Wzb,
                       ushort_t* __restrict__ W1b, ushort_t* __restrict__ W2b,
                       ushort_t* __restrict__ encb, ushort_t* __restrict__ decb) {
    const int idx = blockIdx.x * 256 + threadIdx.x;   // 0..4*512*512-1
    const int k = idx & 511, n = (idx >> 9) & 511, l = idx >> 18;
    {
        const int s = n >> 1, part = n & 1;
        const float* src = part ? Bim : Bre;
        WBb[idx] = f2bf(src[((size_t)l * DS + s) * DM + k]);
    }
    {
        const int s = k >> 1, part = k & 1;
        float v = part ? -Cim[((size_t)l * DM + n) * DS + s]
                       :  Cre[((size_t)l * DM + n) * DS + s];
        Wzb[idx] = f2bf(v);
    }
    W1b[idx] = f2bf(W1[idx]);
    W2b[idx] = f2bf(W2[idx]);
    if (idx < DM * 64) { encb[idx] = f2bf(enc[idx]); decb[idx] = f2bf(dec[idx]); }
}

__global__ void prep_u(const float* __restrict__ u, ushort_t* __restrict__ ubf) {
    const int idx = blockIdx.x * 256 + threadIdx.x;
    ubf[idx] = f2bf(u[idx]);
}

__global__ void prep_tab(const float* __restrict__ nu, const float* __restrict__ th,
                         float* __restrict__ lre, float* __restrict__ lim,
                         float* __restrict__ gm) {
    const int idx = blockIdx.x * 256 + threadIdx.x;   // NL*DS
    float a = expf(-expf(nu[idx])), t = expf(th[idx]);
    lre[idx] = a * cosf(t);
    lim[idx] = a * sinf(t);
    gm[idx] = sqrtf(fmaxf(0.f, 1.f - a * a));
}

// ---------------------------------------------------------------------------
// Scans over interleaved bf16 (re,im) uints. Bu rows have DS uints.
// ---------------------------------------------------------------------------
__global__ void scan_ends(const uint_t* __restrict__ Bu, const float* __restrict__ lre_,
                          const float* __restrict__ lim_, float* __restrict__ carry) {
    const int s = threadIdx.x;
    const int blk = blockIdx.x, b = blk >> 5, c = blk & 31;
    const float lre = lre_[s], lim = lim_[s];
    float hre = 0.f, him = 0.f;
    size_t base = ((size_t)b * SEQ + (size_t)c * LCHUNK) * DS + s;
#pragma unroll 8
    for (int i = 0; i < LCHUNK; ++i, base += DS) {
        uint_t u = Bu[base];
        float br = bf2f(u), bi = bf2f(u >> 16);
        float nr = fmaf(lre, hre, fmaf(-lim, him, br));
        float ni = fmaf(lre, him, fmaf(lim, hre, bi));
        hre = nr; him = ni;
    }
    carry[(size_t)blk * 512 + s] = hre;
    carry[(size_t)blk * 512 + DS + s] = him;
}

__global__ void scan_carry(float* __restrict__ carry, const float* __restrict__ lre_,
                           const float* __restrict__ lim_) {
    const int s = threadIdx.x, b = blockIdx.x;
    float pre = lre_[s], pim = lim_[s];
    for (int t = 0; t < 6; ++t) {            // lam^64
        float nr = pre * pre - pim * pim, ni = 2.f * pre * pim;
        pre = nr; pim = ni;
    }
    size_t base = (size_t)b * NCHUNK * 512 + s;
    float gre = carry[base], gim = carry[base + DS];
    for (int c = 1; c < NCHUNK; ++c) {
        size_t id = base + (size_t)c * 512;
        float cr = carry[id], ci = carry[id + DS];
        float nr = fmaf(pre, gre, fmaf(-pim, gim, cr));
        float ni = fmaf(pre, gim, fmaf(pim, gre, ci));
        gre = nr; gim = ni;
        carry[id] = gre; carry[id + DS] = gim;
    }
}

__global__ void scan_apply(const uint_t* __restrict__ Bu, const float* __restrict__ lre_,
                           const float* __restrict__ lim_, const float* __restrict__ carry,
                           uint_t* __restrict__ h) {
    const int s = threadIdx.x;
    const int blk = blockIdx.x, b = blk >> 5, c = blk & 31;
    const float lre = lre_[s], lim = lim_[s];
    float hre = 0.f, him = 0.f;
    if (c > 0) {
        size_t cb = (size_t)(blk - 1) * 512 + s;
        hre = carry[cb]; him = carry[cb + DS];
    }
    size_t base = ((size_t)b * SEQ + (size_t)c * LCHUNK) * DS + s;
#pragma unroll 8
    for (int i = 0; i < LCHUNK; ++i, base += DS) {
        uint_t u = Bu[base];
        float br = bf2f(u), bi = bf2f(u >> 16);
        float nr = fmaf(lre, hre, fmaf(-lim, him, br));
        float ni = fmaf(lre, him, fmaf(lim, hre, bi));
        hre = nr; him = ni;
        h[base] = pack2(hre, him);
    }
}

// ---------------------------------------------------------------------------
extern "C" void kernel_launch(void* const* d_in, const int* in_sizes, int n_in,
                              void* d_out, int out_size, void* d_ws, size_t ws_size,
                              hipStream_t stream) {
    const float* u   = (const float*)d_in[0];
    const float* enc = (const float*)d_in[1];
    const float* dec = (const float*)d_in[2];
    const float* nu  = (const float*)d_in[3];
    const float* th  = (const float*)d_in[4];
    const float* Bre = (const float*)d_in[5];
    const float* Bim = (const float*)d_in[6];
    const float* Cre = (const float*)d_in[7];
    const float* Cim = (const float*)d_in[8];
    const float* Dp  = (const float*)d_in[9];
    const float* W1  = (const float*)d_in[10];
    const float* W2  = (const float*)d_in[11];
    const float* res = (const float*)d_in[12];
    float* out = (float*)d_out;

    const size_t MD = (size_t)MROWS * DM;
    float* x     = (float*)d_ws;                         // [16384,512] fp32
    float* carry = x + MD;                               // [256,512]
    float* lre   = carry + (size_t)BATCH * NCHUNK * 512;
    float* lim   = lre + NL * DS;
    float* gmt   = lim + NL * DS;
    ushort_t* xbf  = (ushort_t*)(gmt + NL * DS);         // [16384,512] bf16 each:
    ushort_t* Bubf = xbf + MD;
    ushort_t* hbf  = Bubf + MD;
    ushort_t* zbf  = hbf + MD;
    ushort_t* ubf  = zbf;                                // alias: z written after u consumed
    ushort_t* WBb  = zbf + MD;                           // weights, 4x512x512 bf16 each:
    ushort_t* Wzb  = WBb + (size_t)NL * DM * DM;
    ushort_t* W1b  = Wzb + (size_t)NL * DM * DM;
    ushort_t* W2b  = W1b + (size_t)NL * DM * DM;
    ushort_t* encb = W2b + (size_t)NL * DM * DM;         // 512x64
    ushort_t* decb = encb + DM * 64;                     // 64x512

    prep_w<<<NL * DM * DM / 256, 256, 0, stream>>>(Bre, Bim, Cre, Cim, W1, W2, enc, dec,
                                                   WBb, Wzb, W1b, W2b, encb, decb);
    prep_u<<<MROWS * 64 / 256, 256, 0, stream>>>(u, ubf);
    prep_tab<<<NL, 256, 0, stream>>>(nu, th, lre, lim, gmt);

    // encoder: x(f32+bf16) = u @ enc^T
    mgemm<128, 0, 0><<<dim3(MROWS / 128, DM / 128), 256, 0, stream>>>(
        ubf, encb, nullptr, 64, DM, x, xbf, nullptr, nullptr, nullptr, nullptr, 0);

    for (int k = 0; k < NL; ++k) {
        // Bu (interleaved re/im cols, gamma-scaled) -> Bubf
        mgemm<128, 1, 0><<<dim3(MROWS / 128, DM / 128), 256, 0, stream>>>(
            xbf, WBb + (size_t)k * DM * DM, nullptr, DM, DM, nullptr, Bubf,
            gmt + k * DS, nullptr, nullptr, nullptr, 0);
        scan_ends<<<BATCH * NCHUNK, 256, 0, stream>>>((const uint_t*)Bubf,
                                                      lre + k * DS, lim + k * DS, carry);
        scan_carry<<<BATCH, 256, 0, stream>>>(carry, lre + k * DS, lim + k * DS);
        scan_apply<<<BATCH * NCHUNK, 256, 0, stream>>>((const uint_t*)Bubf,
                                                       lre + k * DS, lim + k * DS, carry,
                                                       (uint_t*)hbf);
        // z = Re(h @ C^T) + D*x  -> zbf
        mgemm<128, 2, 0><<<dim3(MROWS / 128, DM / 128), 256, 0, stream>>>(
            hbf, Wzb + (size_t)k * DM * DM, nullptr, DM, DM, nullptr, zbf,
            nullptr, Dp + k * DM, x, nullptr, 0);
        // x += sig(res)*[(z@W1^T)*sigmoid(z@W2^T)]  -> x fp32 + xbf
        mgemm<128, 3, 1><<<dim3(MROWS / 128, DM / 128), 256, 0, stream>>>(
            zbf, W1b + (size_t)k * DM * DM, W2b + (size_t)k * DM * DM, DM, DM,
            nullptr, xbf, nullptr, nullptr, x, res, k);
    }
    // decoder: out = x @ dec^T
    mgemm<64, 4, 0><<<dim3(MROWS / 128, 1), 256, 0, stream>>>(
        xbf, decb, nullptr, DM, 64, out, nullptr, nullptr, nullptr, nullptr, nullptr, 0);
}